// Round 10
// baseline (332.896 us; speedup 1.0000x reference)
//
#include <hip/hip_runtime.h>
#include <hip/hip_bf16.h>
#include <math.h>

typedef __bf16 bf16_t;
typedef __bf16 bf16x8 __attribute__((ext_vector_type(8)));
typedef __bf16 bf16x4 __attribute__((ext_vector_type(4)));
typedef float  f32x4  __attribute__((ext_vector_type(4)));
typedef long   i64_t;
typedef unsigned long long u64_t;

#define D 768

// ---------------- block reduction helpers (blockDim == 256) ----------------
__device__ inline double blk_sum(double x, double* s) {
#pragma unroll
  for (int m = 32; m; m >>= 1) x += __shfl_xor(x, m);
  __syncthreads();
  if ((threadIdx.x & 63) == 0) s[threadIdx.x >> 6] = x;
  __syncthreads();
  return s[0] + s[1] + s[2] + s[3];
}

__device__ inline double blk_max(double x, double* s) {
#pragma unroll
  for (int m = 32; m; m >>= 1) x = fmax(x, __shfl_xor(x, m));
  __syncthreads();
  if ((threadIdx.x & 63) == 0) s[threadIdx.x >> 6] = x;
  __syncthreads();
  return fmax(fmax(s[0], s[1]), fmax(s[2], s[3]));
}

// ---------------- K1: fused normalize for T (fp8 transposed), TS, SUP ------
__global__ __launch_bounds__(256) void norm_all(
    const float* __restrict__ Tm, const float* __restrict__ TS,
    const float* __restrict__ SUP, u64_t* __restrict__ t8T,
    float* __restrict__ ts_n, bf16_t* __restrict__ ts_bf,
    float* __restrict__ sup_n, int U, int B, int Q, int nbT, int nbTS) {
  const int wave = threadIdx.x >> 6, lane = threadIdx.x & 63;
  const int bid = blockIdx.x;

  if (bid < nbT) {  // ---- T: norm + fp8(x16) + transpose to [96][1024] ----
    const int row = bid * 4 + wave;  // 0..1023 (valid < U)
    double inv = 0.0;
    if (row < U) {
      const float4* s = (const float4*)(Tm + (size_t)row * D);
      double ss = 0.0;
#pragma unroll
      for (int j = 0; j < 3; j++) {
        float4 v = s[lane + 64 * j];
        ss += (double)v.x * v.x + (double)v.y * v.y +
              (double)v.z * v.z + (double)v.w * v.w;
      }
#pragma unroll
      for (int m = 32; m; m >>= 1) ss += __shfl_xor(ss, m);
      inv = 1.0 / fmax(sqrt(ss), 1e-12);
    }
    const float sc = (float)(inv * 16.0);
#pragma unroll
    for (int h = 0; h < 2; h++) {
      if (h == 1 && lane >= 32) continue;
      const int c = h * 64 + lane;  // chunk 0..95
      u64_t frag = 0ull;
      if (row < U) {
        const float* p = Tm + (size_t)row * D + c * 8;
        float4 x = *(const float4*)p;
        float4 y = *(const float4*)(p + 4);
        int lo = __builtin_amdgcn_cvt_pk_fp8_f32(x.x * sc, x.y * sc, 0, false);
        lo = __builtin_amdgcn_cvt_pk_fp8_f32(x.z * sc, x.w * sc, lo, true);
        int hi = __builtin_amdgcn_cvt_pk_fp8_f32(y.x * sc, y.y * sc, 0, false);
        hi = __builtin_amdgcn_cvt_pk_fp8_f32(y.z * sc, y.w * sc, hi, true);
        frag = ((u64_t)(unsigned)hi << 32) | (unsigned)lo;
      }
      t8T[(size_t)c * 1024 + row] = frag;
    }
    return;
  }

  const float* src;
  int row;
  bool is_ts = false;
  if (bid < nbT + nbTS) { row = (bid - nbT) * 4 + wave; src = TS; is_ts = true; }
  else                  { row = (bid - nbT - nbTS) * 4 + wave; src = SUP;
                          if (row >= Q) return; }

  const float4* s = (const float4*)(src + (size_t)row * D);
  float4 v[3];
  double ss = 0.0;
#pragma unroll
  for (int j = 0; j < 3; j++) {
    v[j] = s[lane + 64 * j];
    ss += (double)v[j].x * v[j].x + (double)v[j].y * v[j].y +
          (double)v[j].z * v[j].z + (double)v[j].w * v[j].w;
  }
#pragma unroll
  for (int m = 32; m; m >>= 1) ss += __shfl_xor(ss, m);
  double inv = 1.0 / fmax(sqrt(ss), 1e-12);
  float4 o[3];
#pragma unroll
  for (int j = 0; j < 3; j++) {
    o[j].x = (float)((double)v[j].x * inv);
    o[j].y = (float)((double)v[j].y * inv);
    o[j].z = (float)((double)v[j].z * inv);
    o[j].w = (float)((double)v[j].w * inv);
  }
  float* dst_f32 = is_ts ? ts_n : sup_n;
  float* drow = dst_f32 + (size_t)row * D;
#pragma unroll
  for (int j = 0; j < 3; j++) ((float4*)drow)[lane + 64 * j] = o[j];
  if (is_ts) {
    bf16_t* brow = ts_bf + (size_t)row * D;
#pragma unroll
    for (int j = 0; j < 3; j++) {
      bf16x4 ob;
      ob[0] = (bf16_t)o[j].x; ob[1] = (bf16_t)o[j].y;
      ob[2] = (bf16_t)o[j].z; ob[3] = (bf16_t)o[j].w;
      *(bf16x4*)(brow + 4 * (lane + 64 * j)) = ob;
    }
  }
}

// ---------------- K2: max-sim GEMM v10 (fp8, L2-streamed B, no LDS) --------
// 128 W-rows/block (4 waves x 2 row-tiles of 16), r=2 register-resident A
// (raw f32 -> e4m3 in regs, f32 row-norm fused). B fragments are read
// DIRECTLY from the transposed t8T (768 KB -> L2-resident on every XCD):
// per tile 24 coalesced b64 loads feed 48 MFMAs. No LDS, no barriers --
// waves run free; compiler pipelines the load batches with counted vmcnt.
// gridDim.y = 2 U-halves for block supply; W read once (L3 absorbs pass 2).
__global__ __launch_bounds__(256) void maxsim_gemm(
    const float* __restrict__ W, const u64_t* __restrict__ T8T,
    float* __restrict__ maxpart, int V, int U, int NT, int vstride) {
  const int tid  = threadIdx.x;
  const int lane = tid & 63;
  const int r    = lane & 15;   // row-within-tile (A), proto col (C)
  const int ks   = lane >> 4;   // k-slice 0..3
  const int rowbase = blockIdx.x * 128 + (tid >> 6) * 32;
  const int row0 = rowbase + r;
  const int row1 = rowbase + 16 + r;

  // ---- A load (raw f32 -> e4m3) + fused row-norms ----
  i64_t a0[24], a1[24];
  float ss0 = 0.f, ss1 = 0.f;
  {
    const float* p0 = W + (size_t)row0 * D + ks * 8;
    const float* p1 = W + (size_t)row1 * D + ks * 8;
    const bool v0 = row0 < V, v1 = row1 < V;
#pragma unroll
    for (int kk = 0; kk < 24; kk++) {
      i64_t f = 0;
      if (v0) {
        float4 x = *(const float4*)(p0 + kk * 32);
        float4 y = *(const float4*)(p0 + kk * 32 + 4);
        ss0 += x.x * x.x + x.y * x.y + x.z * x.z + x.w * x.w +
               y.x * y.x + y.y * y.y + y.z * y.z + y.w * y.w;
        int lo = __builtin_amdgcn_cvt_pk_fp8_f32(x.x, x.y, 0, false);
        lo = __builtin_amdgcn_cvt_pk_fp8_f32(x.z, x.w, lo, true);
        int hi = __builtin_amdgcn_cvt_pk_fp8_f32(y.x, y.y, 0, false);
        hi = __builtin_amdgcn_cvt_pk_fp8_f32(y.z, y.w, hi, true);
        f = ((i64_t)hi << 32) | (i64_t)(unsigned int)lo;
      }
      a0[kk] = f;
      f = 0;
      if (v1) {
        float4 x = *(const float4*)(p1 + kk * 32);
        float4 y = *(const float4*)(p1 + kk * 32 + 4);
        ss1 += x.x * x.x + x.y * x.y + x.z * x.z + x.w * x.w +
               y.x * y.x + y.y * y.y + y.z * y.z + y.w * y.w;
        int lo = __builtin_amdgcn_cvt_pk_fp8_f32(x.x, x.y, 0, false);
        lo = __builtin_amdgcn_cvt_pk_fp8_f32(x.z, x.w, lo, true);
        int hi = __builtin_amdgcn_cvt_pk_fp8_f32(y.x, y.y, 0, false);
        hi = __builtin_amdgcn_cvt_pk_fp8_f32(y.z, y.w, hi, true);
        f = ((i64_t)hi << 32) | (i64_t)(unsigned int)lo;
      }
      a1[kk] = f;
    }
  }
  ss0 += __shfl_xor(ss0, 16); ss0 += __shfl_xor(ss0, 32);
  ss1 += __shfl_xor(ss1, 16); ss1 += __shfl_xor(ss1, 32);
  const double inv0 = 1.0 / fmax(sqrt((double)ss0), 1e-12);
  const double inv1 = 1.0 / fmax(sqrt((double)ss1), 1e-12);

  const int t0   = blockIdx.y * 32;
  const int tend = min(NT, t0 + 32);

  // lane's B base: t8T[(kk*4+ks)*1024 + nt*16 + r]
  const u64_t* bp = T8T + (size_t)ks * 1024 + r;

  f32x4 mx0 = {-1e30f, -1e30f, -1e30f, -1e30f};
  f32x4 mx1 = {-1e30f, -1e30f, -1e30f, -1e30f};
  for (int nt = t0; nt < tend; nt++) {
    const u64_t* bnt = bp + (size_t)nt * 16;
    u64_t bv[24];
#pragma unroll
    for (int kk = 0; kk < 24; kk++) bv[kk] = bnt[(size_t)kk * 4096];
    f32x4 ac0 = {0.f, 0.f, 0.f, 0.f}, ac1 = {0.f, 0.f, 0.f, 0.f};
#pragma unroll
    for (int kk = 0; kk < 24; kk++) {
      ac0 = __builtin_amdgcn_mfma_f32_16x16x32_fp8_fp8(a0[kk], (i64_t)bv[kk], ac0, 0, 0, 0);
      ac1 = __builtin_amdgcn_mfma_f32_16x16x32_fp8_fp8(a1[kk], (i64_t)bv[kk], ac1, 0, 0, 0);
    }
    if (nt * 16 + r < U) {
#pragma unroll
      for (int j = 0; j < 4; j++) {
        mx0[j] = fmaxf(mx0[j], ac0[j]);
        mx1[j] = fmaxf(mx1[j], ac1[j]);
      }
    }
  }
  // reduce across the 16 proto-lanes (C layout: col=lane&15, row=ks*4+j)
#pragma unroll
  for (int m = 1; m < 16; m <<= 1) {
#pragma unroll
    for (int j = 0; j < 4; j++) {
      mx0[j] = fmaxf(mx0[j], __shfl_xor(mx0[j], m));
      mx1[j] = fmaxf(mx1[j], __shfl_xor(mx1[j], m));
    }
  }
  float res0[4], res1[4];
#pragma unroll
  for (int j = 0; j < 4; j++) {
    int rr = ks * 4 + j;
    double iv0 = __shfl(inv0, rr);  // row rowbase+rr's norm lives in lane rr
    double iv1 = __shfl(inv1, rr);
    res0[j] = (float)((double)mx0[j] * iv0 * (1.0 / 16.0));
    res1[j] = (float)((double)mx1[j] * iv1 * (1.0 / 16.0));
  }
  if (r == 0) {
#pragma unroll
    for (int j = 0; j < 4; j++) {
      int rr = ks * 4 + j;
      if (rowbase + rr < V)
        maxpart[blockIdx.y * vstride + rowbase + rr] = res0[j];
      if (rowbase + 16 + rr < V)
        maxpart[blockIdx.y * vstride + rowbase + 16 + rr] = res1[j];
    }
  }
}

// ---------------- K3: approx sim GEMM (bf16 MFMA) ---------------------------
#define LDSROW 776  // 768 + 8 pad (bf16 units)

__global__ __launch_bounds__(256) void simf_gemm(const float* __restrict__ SUPn,
                                                 const bf16_t* __restrict__ TSb,
                                                 float* __restrict__ sim,
                                                 int Q, int ld, int NTB) {
  __shared__ __align__(16) bf16_t lds[2][16 * LDSROW];
  const int tid  = threadIdx.x;
  const int lane = tid & 63;
  const int rowbase = blockIdx.x * 64 + (tid >> 6) * 16;
  const int arow_i  = rowbase + (lane & 15);

  bf16x8 a[24];
  if (arow_i < Q) {
    const float* ar = SUPn + (size_t)arow_i * D + ((lane >> 4) * 8);
#pragma unroll
    for (int kk = 0; kk < 24; kk++) {
      float4 x = *(const float4*)(ar + kk * 32);
      float4 y = *(const float4*)(ar + kk * 32 + 4);
      bf16x8 f;
      f[0] = (bf16_t)x.x; f[1] = (bf16_t)x.y; f[2] = (bf16_t)x.z; f[3] = (bf16_t)x.w;
      f[4] = (bf16_t)y.x; f[5] = (bf16_t)y.y; f[6] = (bf16_t)y.z; f[7] = (bf16_t)y.w;
      a[kk] = f;
    }
  } else {
#pragma unroll
    for (int kk = 0; kk < 24; kk++) {
      bf16x8 f;
#pragma unroll
      for (int e = 0; e < 8; e++) f[e] = (bf16_t)0.f;
      a[kk] = f;
    }
  }

  auto stage = [&](int buf, int nt) {
    const ulonglong2* src = (const ulonglong2*)(TSb + (size_t)nt * 16 * D);
#pragma unroll
    for (int j = 0; j < 6; j++) {
      int c = tid + j * 256;
      int rr = c / 96, w = c % 96;
      *(ulonglong2*)&lds[buf][rr * LDSROW + w * 8] = src[c];
    }
  };

  stage(0, 0);
  for (int nt = 0; nt < NTB; nt++) {
    __syncthreads();
    if (nt + 1 < NTB) stage((nt + 1) & 1, nt + 1);
    f32x4 acc = {0.f, 0.f, 0.f, 0.f};
    const bf16_t* brow = &lds[nt & 1][(lane & 15) * LDSROW + ((lane >> 4) * 8)];
#pragma unroll
    for (int kk = 0; kk < 24; kk++) {
      bf16x8 b = *(const bf16x8*)(brow + kk * 32);
      acc = __builtin_amdgcn_mfma_f32_16x16x32_bf16(a[kk], b, acc, 0, 0, 0);
    }
    const int bcol = nt * 16 + (lane & 15);
    const int q0   = rowbase + ((lane >> 4) << 2);
    float* dst = sim + (size_t)bcol * ld + q0;
    if (q0 + 3 < Q) {
      *(f32x4*)dst = acc;
    } else {
#pragma unroll
      for (int j = 0; j < 4; j++)
        if (q0 + j < Q) dst[j] = acc[j];
    }
  }
}

// ---------------- K4: top-16 + f64 rescore + gather + pos + NNCL -----------
__device__ inline unsigned long long pack_key(float v, int q) {
  unsigned u = __float_as_uint(v);
  u = (u & 0x80000000u) ? ~u : (u | 0x80000000u);  // order-preserving map
  return ((unsigned long long)u << 32) | (unsigned)(0xFFFFFFFFu - (unsigned)q);
}

__global__ __launch_bounds__(256) void topk_nncl(const float* __restrict__ sim,
                                                 const float* __restrict__ SUPn,
                                                 const float* __restrict__ TSn,
                                                 float* __restrict__ out,
                                                 double* __restrict__ row_loss,
                                                 int Q, int ld) {
  __shared__ unsigned long long sk[256][16];
  __shared__ float tsrow[D];
  __shared__ double sval[16];
  __shared__ int    sidx[16];
  __shared__ double red[4];
  const int b = blockIdx.x, tid = threadIdx.x;
#pragma unroll
  for (int j = 0; j < 3; j++) tsrow[tid + 256 * j] = TSn[(size_t)b * D + tid + 256 * j];

  const float* row = sim + (size_t)b * ld;
  unsigned long long best[16];
#pragma unroll
  for (int k = 0; k < 16; k++) best[k] = 0ull;
  for (int q = tid; q < Q; q += 256) {
    unsigned long long key = pack_key(row[q], q);
    if (key > best[15]) {
      best[15] = key;
      for (int k = 15; k > 0; k--) {
        if (best[k] > best[k - 1]) {
          unsigned long long t = best[k]; best[k] = best[k - 1]; best[k - 1] = t;
        } else break;
      }
    }
  }
#pragma unroll
  for (int k = 0; k < 16; k++) sk[tid][k] = best[k];
  for (int stride = 128; stride >= 1; stride >>= 1) {
    __syncthreads();
    if (tid < stride) {
      unsigned long long outk[16];
      int pa = 0, pb = 0;
#pragma unroll
      for (int k = 0; k < 16; k++) {
        unsigned long long va = sk[tid][pa], vb = sk[tid + stride][pb];
        if (va >= vb) { outk[k] = va; pa++; }
        else          { outk[k] = vb; pb++; }
      }
#pragma unroll
      for (int k = 0; k < 16; k++) sk[tid][k] = outk[k];
    }
  }
  __syncthreads();

  // exact f64 rescore of the 16 candidates (1 wave each, 4 rounds)
  const int lane = tid & 63, w = tid >> 6;
  for (int c = w; c < 16; c += 4) {
    int q = (int)(0xFFFFFFFFu - (unsigned)(sk[0][c] & 0xFFFFFFFFull));
    const float* sr = SUPn + (size_t)q * D;
    double dot = 0.0;
#pragma unroll
    for (int i = 0; i < 12; i++)
      dot += (double)sr[lane + 64 * i] * (double)tsrow[lane + 64 * i];
#pragma unroll
    for (int m = 32; m; m >>= 1) dot += __shfl_xor(dot, m);
    if (lane == 0) { sval[c] = dot; sidx[c] = q; }
  }
  __syncthreads();
  if (tid == 0) {
    for (int i = 1; i < 16; i++) {
      double v = sval[i]; int ix = sidx[i];
      int j = i - 1;
      while (j >= 0 && (sval[j] < v || (sval[j] == v && sidx[j] > ix))) {
        sval[j + 1] = sval[j]; sidx[j + 1] = sidx[j]; j--;
      }
      sval[j + 1] = v; sidx[j + 1] = ix;
    }
  }
  __syncthreads();

  // gather top-8 rows to output + positive mean + pos_sim
  float mean[3] = {0.f, 0.f, 0.f};
#pragma unroll
  for (int k = 0; k < 8; k++) {
    const float* sr = SUPn + (size_t)sidx[k] * D;
    float* orow = out + ((size_t)b * 8 + k) * D;
#pragma unroll
    for (int j = 0; j < 3; j++) {
      float x = sr[tid + 256 * j];
      orow[tid + 256 * j] = x;
      mean[j] += x;
    }
  }
#pragma unroll
  for (int j = 0; j < 3; j++) mean[j] *= 0.125f;
  double ss = 0.0;
#pragma unroll
  for (int j = 0; j < 3; j++) ss += (double)mean[j] * mean[j];
  ss = blk_sum(ss, red);
  double inv = 1.0 / fmax(sqrt(ss), 1e-12);
  double dot = 0.0;
#pragma unroll
  for (int j = 0; j < 3; j++)
    dot += (double)tsrow[tid + 256 * j] * ((double)mean[j] * inv);
  dot = blk_sum(dot, red);
  const double p = dot / (double)0.07f;

  // NNCL logsumexp over columns c = tid
  const float* tc = TSn + (size_t)tid * D;
  double dot2 = 0.0;
  for (int e = 0; e < D; e += 4) {
    float4 t4 = *(const float4*)(tc + e);
    dot2 += (double)tsrow[e] * t4.x + (double)tsrow[e + 1] * t4.y +
            (double)tsrow[e + 2] * t4.z + (double)tsrow[e + 3] * t4.w;
  }
  const bool diag = (tid == b);
  double logit = dot2 / (double)0.07f;
  double m = blk_max(diag ? -1e300 : logit, red);
  m = fmax(m, p);
  double term = diag ? 0.0 : exp(logit - m);
  double ssum = blk_sum(term, red);
  ssum += exp(p - m);
  if (tid == 0) row_loss[b] = (log(ssum) + m) - p;
}

// ---------------- K5: finalize scalars --------------------------------------
__global__ __launch_bounds__(256) void finalize(const float* __restrict__ maxpart,
                                                const double* __restrict__ row_loss,
                                                float* __restrict__ d_out, int out_size,
                                                int V, int B, int vstride) {
  __shared__ double red[4];
  const int tid = threadIdx.x;
  double s1 = 0.0;
  for (int v = tid; v < V; v += 256) {
    float mx = fmaxf(maxpart[v], maxpart[vstride + v]);
    s1 += 2.0 - 2.0 * (double)mx;
  }
  s1 = blk_sum(s1, red);
  __syncthreads();
  double s2 = 0.0;
  for (int b = tid; b < B; b += 256) s2 += row_loss[b];
  s2 = blk_sum(s2, red);
  if (tid == 0) {
    d_out[out_size - 2] = (float)(s1 / ((double)V * (double)D));
    d_out[out_size - 1] = (float)(s2 / (double)B);
  }
}

// ---------------- host launcher ---------------------------------------------
extern "C" void kernel_launch(void* const* d_in, const int* in_sizes, int n_in,
                              void* d_out, int out_size, void* d_ws, size_t ws_size,
                              hipStream_t stream) {
  const float* TS  = (const float*)d_in[0];
  const float* W   = (const float*)d_in[1];
  const float* T   = (const float*)d_in[2];
  const float* SUP = (const float*)d_in[3];
  const int B = in_sizes[0] / D;   // 256
  const int V = in_sizes[1] / D;   // 50257
  const int U = in_sizes[2] / D;   // 1000
  const int Q = in_sizes[3] / D;   // 10000
  const int NT   = (U + 15) / 16;  // 63
  const int V128 = (V + 127) & ~127; // 50432
  const int QPAD = (Q + 63) & ~63; // 10048
  const int NTB  = B / 16;         // 16
  const int nbT  = 1024 / 4;       // 256 (T rows padded to 1024)
  const int nbTS = B / 4;          // 64
  const int nbSUP = (Q + 3) / 4;   // 2500

  char* ws = (char*)d_ws;
  size_t off = 0;
  auto alloc = [&](size_t bytes) -> char* {
    char* p = ws + off;
    off = (off + bytes + 255) & ~(size_t)255;
    return p;
  };
  u64_t*  t8T    = (u64_t*) alloc((size_t)96 * 1024 * 8);  // k-major fp8
  float*  maxpart= (float*) alloc((size_t)2 * V128 * 4);
  float*  ts_n   = (float*) alloc((size_t)B * D * 4);
  bf16_t* ts_bf  = (bf16_t*)alloc((size_t)B * D * 2);
  float*  sup_n  = (float*) alloc((size_t)Q * D * 4);
  float*  simf   = (float*) alloc((size_t)B * QPAD * 4);
  double* rloss  = (double*)alloc((size_t)B * 8);
  (void)ws_size; (void)n_in;

  norm_all<<<nbT + nbTS + nbSUP, 256, 0, stream>>>(
      T, TS, SUP, t8T, ts_n, ts_bf, sup_n, U, B, Q, nbT, nbTS);

  dim3 gms(V128 / 128, 2);  // y = U-half
  maxsim_gemm<<<gms, 256, 0, stream>>>(W, t8T, maxpart, V, U, NT, V128);

  simf_gemm<<<QPAD / 64, 256, 0, stream>>>(sup_n, ts_bf, simf, Q, QPAD, NTB);
  topk_nncl<<<B, 256, 0, stream>>>(simf, sup_n, ts_n, (float*)d_out, rloss, Q, QPAD);
  finalize<<<1, 256, 0, stream>>>(maxpart, rloss, (float*)d_out, out_size, V, B, V128);
}

// Round 11
// 303.898 us; speedup vs baseline: 1.0954x; 1.0954x over previous
//
#include <hip/hip_runtime.h>
#include <hip/hip_bf16.h>
#include <math.h>

typedef __bf16 bf16_t;
typedef __bf16 bf16x8 __attribute__((ext_vector_type(8)));
typedef __bf16 bf16x4 __attribute__((ext_vector_type(4)));
typedef float  f32x4  __attribute__((ext_vector_type(4)));
typedef long   i64_t;
typedef unsigned long long u64_t;

#define D 768

// ---------------- block reduction helpers (blockDim == 256) ----------------
__device__ inline double blk_sum(double x, double* s) {
#pragma unroll
  for (int m = 32; m; m >>= 1) x += __shfl_xor(x, m);
  __syncthreads();
  if ((threadIdx.x & 63) == 0) s[threadIdx.x >> 6] = x;
  __syncthreads();
  return s[0] + s[1] + s[2] + s[3];
}

__device__ inline double blk_max(double x, double* s) {
#pragma unroll
  for (int m = 32; m; m >>= 1) x = fmax(x, __shfl_xor(x, m));
  __syncthreads();
  if ((threadIdx.x & 63) == 0) s[threadIdx.x >> 6] = x;
  __syncthreads();
  return fmax(fmax(s[0], s[1]), fmax(s[2], s[3]));
}

// ---------------- K1: fused normalize for T (fp8 row-major), TS, SUP -------
// One wave per row. Block ranges: [0,nbT) = T -> t8 (row-major fp8 x16),
// [nbT, nbT+nbTS) = TS -> ts_n + ts_bf, rest = SUP -> sup_n.
__global__ __launch_bounds__(256) void norm_all(
    const float* __restrict__ Tm, const float* __restrict__ TS,
    const float* __restrict__ SUP, unsigned int* __restrict__ t8,
    float* __restrict__ ts_n, bf16_t* __restrict__ ts_bf,
    float* __restrict__ sup_n, int U, int B, int Q, int nbT, int nbTS) {
  const int wave = threadIdx.x >> 6, lane = threadIdx.x & 63;
  const int bid = blockIdx.x;

  if (bid < nbT) {  // ---- T: norm + fp8(x16), row-major [1008][768] --------
    const int row = bid * 4 + wave;
    unsigned int* drow = t8 + (size_t)row * (D / 4);
    if (row >= U) {
#pragma unroll
      for (int j = 0; j < 3; j++) drow[lane + 64 * j] = 0u;
      return;
    }
    const float4* s = (const float4*)(Tm + (size_t)row * D);
    float4 v[3];
    double ss = 0.0;
#pragma unroll
    for (int j = 0; j < 3; j++) {
      v[j] = s[lane + 64 * j];
      ss += (double)v[j].x * v[j].x + (double)v[j].y * v[j].y +
            (double)v[j].z * v[j].z + (double)v[j].w * v[j].w;
    }
#pragma unroll
    for (int m = 32; m; m >>= 1) ss += __shfl_xor(ss, m);
    const float sc = (float)(16.0 / fmax(sqrt(ss), 1e-12));
#pragma unroll
    for (int j = 0; j < 3; j++) {
      int pk = __builtin_amdgcn_cvt_pk_fp8_f32(v[j].x * sc, v[j].y * sc, 0, false);
      pk = __builtin_amdgcn_cvt_pk_fp8_f32(v[j].z * sc, v[j].w * sc, pk, true);
      drow[lane + 64 * j] = (unsigned int)pk;
    }
    return;
  }

  const float* src;
  int row;
  bool is_ts = false;
  if (bid < nbT + nbTS) { row = (bid - nbT) * 4 + wave; src = TS; is_ts = true; }
  else                  { row = (bid - nbT - nbTS) * 4 + wave; src = SUP;
                          if (row >= Q) return; }

  const float4* s = (const float4*)(src + (size_t)row * D);
  float4 v[3];
  double ss = 0.0;
#pragma unroll
  for (int j = 0; j < 3; j++) {
    v[j] = s[lane + 64 * j];
    ss += (double)v[j].x * v[j].x + (double)v[j].y * v[j].y +
          (double)v[j].z * v[j].z + (double)v[j].w * v[j].w;
  }
#pragma unroll
  for (int m = 32; m; m >>= 1) ss += __shfl_xor(ss, m);
  double inv = 1.0 / fmax(sqrt(ss), 1e-12);
  float4 o[3];
#pragma unroll
  for (int j = 0; j < 3; j++) {
    o[j].x = (float)((double)v[j].x * inv);
    o[j].y = (float)((double)v[j].y * inv);
    o[j].z = (float)((double)v[j].z * inv);
    o[j].w = (float)((double)v[j].w * inv);
  }
  float* dst_f32 = is_ts ? ts_n : sup_n;
  float* drow = dst_f32 + (size_t)row * D;
#pragma unroll
  for (int j = 0; j < 3; j++) ((float4*)drow)[lane + 64 * j] = o[j];
  if (is_ts) {
    bf16_t* brow = ts_bf + (size_t)row * D;
#pragma unroll
    for (int j = 0; j < 3; j++) {
      bf16x4 ob;
      ob[0] = (bf16_t)o[j].x; ob[1] = (bf16_t)o[j].y;
      ob[2] = (bf16_t)o[j].z; ob[3] = (bf16_t)o[j].w;
      *(bf16x4*)(brow + 4 * (lane + 64 * j)) = ob;
    }
  }
}

// ---------------- K2: max-sim GEMM v11 (fp8, async global_load_lds stage) --
// r7 structure: 64 W-rows/block (4 waves x 16 rows, A register-resident
// e4m3, f32 row-norm fused, row-max / norm at the end). B = 16-proto fp8
// tiles double-buffered in LDS, staged with __builtin_amdgcn_global_load_lds
// (16B, linear LDS dest, PRE-SWIZZLED global source chunk w ^ (row&7)) so
// there is no in-loop vmcnt(0)+ds_write chain; read side applies the same
// XOR (identical to r7's verified read path). gridDim.y = 4 U-quarters.
__global__ __launch_bounds__(256) void maxsim_gemm(
    const float* __restrict__ W, const unsigned char* __restrict__ T8,
    float* __restrict__ maxpart, int V, int U, int NT, int vstride) {
  __shared__ __align__(16) unsigned char lds[2][16 * 768];
  const int tid  = threadIdx.x;
  const int lane = tid & 63;
  const int r    = lane & 15;   // W row within tile (A), proto col (C)
  const int ks   = lane >> 4;   // k-slice 0..3
  const int rowbase = blockIdx.x * 64 + (tid >> 6) * 16;
  const int row0 = rowbase + r;
  const bool va  = row0 < V;
  const int swzr = (r & 7) << 4;

  // ---- A load (raw f32 -> e4m3) + fused row-norm ----
  i64_t a[24];
  float ss = 0.f;
  {
    const float* p0 = W + (size_t)row0 * D + ks * 8;
#pragma unroll
    for (int kk = 0; kk < 24; kk++) {
      i64_t frag = 0;
      if (va) {
        float4 x = *(const float4*)(p0 + kk * 32);
        float4 y = *(const float4*)(p0 + kk * 32 + 4);
        ss += x.x * x.x + x.y * x.y + x.z * x.z + x.w * x.w +
              y.x * y.x + y.y * y.y + y.z * y.z + y.w * y.w;
        int lo = __builtin_amdgcn_cvt_pk_fp8_f32(x.x, x.y, 0, false);
        lo = __builtin_amdgcn_cvt_pk_fp8_f32(x.z, x.w, lo, true);
        int hi = __builtin_amdgcn_cvt_pk_fp8_f32(y.x, y.y, 0, false);
        hi = __builtin_amdgcn_cvt_pk_fp8_f32(y.z, y.w, hi, true);
        frag = ((i64_t)hi << 32) | (i64_t)(unsigned int)lo;
      }
      a[kk] = frag;
    }
  }
  ss += __shfl_xor(ss, 16);
  ss += __shfl_xor(ss, 32);
  const double inv = 1.0 / fmax(sqrt((double)ss), 1e-12);

  // async stage: 768 x 16B chunks per tile; LDS linear, source pre-swizzled
  const int wv = tid >> 6;
  auto stage = [&](int buf, int nt) {
    const unsigned char* base = T8 + (size_t)nt * (16 * 768);
#pragma unroll
    for (int j = 0; j < 3; j++) {
      const int idx = j * 256 + tid;          // 16B-chunk index 0..767
      const int rr = idx / 48, w = idx % 48;  // 48 chunks per proto row
      const unsigned char* src = base + rr * 768 + ((w ^ (rr & 7)) << 4);
      unsigned char* dst = &lds[buf][0] + (size_t)(j * 256 + wv * 64) * 16;
      __builtin_amdgcn_global_load_lds(
          (const __attribute__((address_space(1))) unsigned int*)src,
          (__attribute__((address_space(3))) unsigned int*)dst, 16, 0, 0);
    }
  };

  const int t0   = blockIdx.y * 16;           // this quarter's tile range
  const int tend = min(NT, t0 + 16);

  f32x4 mx = {-1e30f, -1e30f, -1e30f, -1e30f};
  stage(0, t0);
  for (int nt = t0; nt < tend; nt++) {
    __syncthreads();
    if (nt + 1 < tend) stage((nt + 1) & 1, nt + 1);
    f32x4 ac0 = {0.f,0.f,0.f,0.f}, ac1 = {0.f,0.f,0.f,0.f};
    f32x4 ac2 = {0.f,0.f,0.f,0.f}, ac3 = {0.f,0.f,0.f,0.f};
    const unsigned char* brow = &lds[nt & 1][r * 768];
#pragma unroll
    for (int kk = 0; kk < 24; kk += 4) {
      i64_t b0 = *(const i64_t*)(brow + (((kk + 0) * 32 + ks * 8) ^ swzr));
      i64_t b1 = *(const i64_t*)(brow + (((kk + 1) * 32 + ks * 8) ^ swzr));
      i64_t b2 = *(const i64_t*)(brow + (((kk + 2) * 32 + ks * 8) ^ swzr));
      i64_t b3 = *(const i64_t*)(brow + (((kk + 3) * 32 + ks * 8) ^ swzr));
      ac0 = __builtin_amdgcn_mfma_f32_16x16x32_fp8_fp8(a[kk],     b0, ac0, 0, 0, 0);
      ac1 = __builtin_amdgcn_mfma_f32_16x16x32_fp8_fp8(a[kk + 1], b1, ac1, 0, 0, 0);
      ac2 = __builtin_amdgcn_mfma_f32_16x16x32_fp8_fp8(a[kk + 2], b2, ac2, 0, 0, 0);
      ac3 = __builtin_amdgcn_mfma_f32_16x16x32_fp8_fp8(a[kk + 3], b3, ac3, 0, 0, 0);
    }
    if (nt * 16 + r < U) {
#pragma unroll
      for (int j = 0; j < 4; j++)
        mx[j] = fmaxf(mx[j], (ac0[j] + ac1[j]) + (ac2[j] + ac3[j]));
    }
  }
  // reduce across the 16 proto-lanes (C layout: col=lane&15, row=ks*4+j)
#pragma unroll
  for (int m = 1; m < 16; m <<= 1) {
#pragma unroll
    for (int j = 0; j < 4; j++) mx[j] = fmaxf(mx[j], __shfl_xor(mx[j], m));
  }
#pragma unroll
  for (int j = 0; j < 4; j++) {
    int rr = ks * 4 + j;
    double iv = __shfl(inv, rr);  // row rowbase+rr's norm lives in lane rr
    if (r == 0 && rowbase + rr < V)
      maxpart[blockIdx.y * vstride + rowbase + rr] =
          (float)((double)mx[j] * iv * (1.0 / 16.0));
  }
}

// ---------------- K3: approx sim GEMM (bf16 MFMA) ---------------------------
#define LDSROW 776  // 768 + 8 pad (bf16 units)

__global__ __launch_bounds__(256) void simf_gemm(const float* __restrict__ SUPn,
                                                 const bf16_t* __restrict__ TSb,
                                                 float* __restrict__ sim,
                                                 int Q, int ld, int NTB) {
  __shared__ __align__(16) bf16_t lds[2][16 * LDSROW];
  const int tid  = threadIdx.x;
  const int lane = tid & 63;
  const int rowbase = blockIdx.x * 64 + (tid >> 6) * 16;
  const int arow_i  = rowbase + (lane & 15);

  bf16x8 a[24];
  if (arow_i < Q) {
    const float* ar = SUPn + (size_t)arow_i * D + ((lane >> 4) * 8);
#pragma unroll
    for (int kk = 0; kk < 24; kk++) {
      float4 x = *(const float4*)(ar + kk * 32);
      float4 y = *(const float4*)(ar + kk * 32 + 4);
      bf16x8 f;
      f[0] = (bf16_t)x.x; f[1] = (bf16_t)x.y; f[2] = (bf16_t)x.z; f[3] = (bf16_t)x.w;
      f[4] = (bf16_t)y.x; f[5] = (bf16_t)y.y; f[6] = (bf16_t)y.z; f[7] = (bf16_t)y.w;
      a[kk] = f;
    }
  } else {
#pragma unroll
    for (int kk = 0; kk < 24; kk++) {
      bf16x8 f;
#pragma unroll
      for (int e = 0; e < 8; e++) f[e] = (bf16_t)0.f;
      a[kk] = f;
    }
  }

  auto stage = [&](int buf, int nt) {
    const ulonglong2* src = (const ulonglong2*)(TSb + (size_t)nt * 16 * D);
#pragma unroll
    for (int j = 0; j < 6; j++) {
      int c = tid + j * 256;
      int rr = c / 96, w = c % 96;
      *(ulonglong2*)&lds[buf][rr * LDSROW + w * 8] = src[c];
    }
  };

  stage(0, 0);
  for (int nt = 0; nt < NTB; nt++) {
    __syncthreads();
    if (nt + 1 < NTB) stage((nt + 1) & 1, nt + 1);
    f32x4 acc = {0.f, 0.f, 0.f, 0.f};
    const bf16_t* brow = &lds[nt & 1][(lane & 15) * LDSROW + ((lane >> 4) * 8)];
#pragma unroll
    for (int kk = 0; kk < 24; kk++) {
      bf16x8 b = *(const bf16x8*)(brow + kk * 32);
      acc = __builtin_amdgcn_mfma_f32_16x16x32_bf16(a[kk], b, acc, 0, 0, 0);
    }
    const int bcol = nt * 16 + (lane & 15);
    const int q0   = rowbase + ((lane >> 4) << 2);
    float* dst = sim + (size_t)bcol * ld + q0;
    if (q0 + 3 < Q) {
      *(f32x4*)dst = acc;
    } else {
#pragma unroll
      for (int j = 0; j < 4; j++)
        if (q0 + j < Q) dst[j] = acc[j];
    }
  }
}

// ---------------- K4: top-16 + f64 rescore + gather + pos + NNCL -----------
__device__ inline unsigned long long pack_key(float v, int q) {
  unsigned u = __float_as_uint(v);
  u = (u & 0x80000000u) ? ~u : (u | 0x80000000u);  // order-preserving map
  return ((unsigned long long)u << 32) | (unsigned)(0xFFFFFFFFu - (unsigned)q);
}

__global__ __launch_bounds__(256) void topk_nncl(const float* __restrict__ sim,
                                                 const float* __restrict__ SUPn,
                                                 const float* __restrict__ TSn,
                                                 float* __restrict__ out,
                                                 double* __restrict__ row_loss,
                                                 int Q, int ld) {
  __shared__ unsigned long long sk[256][16];
  __shared__ float tsrow[D];
  __shared__ double sval[16];
  __shared__ int    sidx[16];
  __shared__ double red[4];
  const int b = blockIdx.x, tid = threadIdx.x;
#pragma unroll
  for (int j = 0; j < 3; j++) tsrow[tid + 256 * j] = TSn[(size_t)b * D + tid + 256 * j];

  const float* row = sim + (size_t)b * ld;
  unsigned long long best[16];
#pragma unroll
  for (int k = 0; k < 16; k++) best[k] = 0ull;
  for (int q = tid; q < Q; q += 256) {
    unsigned long long key = pack_key(row[q], q);
    if (key > best[15]) {
      best[15] = key;
      for (int k = 15; k > 0; k--) {
        if (best[k] > best[k - 1]) {
          unsigned long long t = best[k]; best[k] = best[k - 1]; best[k - 1] = t;
        } else break;
      }
    }
  }
#pragma unroll
  for (int k = 0; k < 16; k++) sk[tid][k] = best[k];
  for (int stride = 128; stride >= 1; stride >>= 1) {
    __syncthreads();
    if (tid < stride) {
      unsigned long long outk[16];
      int pa = 0, pb = 0;
#pragma unroll
      for (int k = 0; k < 16; k++) {
        unsigned long long va = sk[tid][pa], vb = sk[tid + stride][pb];
        if (va >= vb) { outk[k] = va; pa++; }
        else          { outk[k] = vb; pb++; }
      }
#pragma unroll
      for (int k = 0; k < 16; k++) sk[tid][k] = outk[k];
    }
  }
  __syncthreads();

  // exact f64 rescore of the 16 candidates (1 wave each, 4 rounds)
  const int lane = tid & 63, w = tid >> 6;
  for (int c = w; c < 16; c += 4) {
    int q = (int)(0xFFFFFFFFu - (unsigned)(sk[0][c] & 0xFFFFFFFFull));
    const float* sr = SUPn + (size_t)q * D;
    double dot = 0.0;
#pragma unroll
    for (int i = 0; i < 12; i++)
      dot += (double)sr[lane + 64 * i] * (double)tsrow[lane + 64 * i];
#pragma unroll
    for (int m = 32; m; m >>= 1) dot += __shfl_xor(dot, m);
    if (lane == 0) { sval[c] = dot; sidx[c] = q; }
  }
  __syncthreads();
  if (tid == 0) {
    for (int i = 1; i < 16; i++) {
      double v = sval[i]; int ix = sidx[i];
      int j = i - 1;
      while (j >= 0 && (sval[j] < v || (sval[j] == v && sidx[j] > ix))) {
        sval[j + 1] = sval[j]; sidx[j + 1] = sidx[j]; j--;
      }
      sval[j + 1] = v; sidx[j + 1] = ix;
    }
  }
  __syncthreads();

  // gather top-8 rows to output + positive mean + pos_sim
  float mean[3] = {0.f, 0.f, 0.f};
#pragma unroll
  for (int k = 0; k < 8; k++) {
    const float* sr = SUPn + (size_t)sidx[k] * D;
    float* orow = out + ((size_t)b * 8 + k) * D;
#pragma unroll
    for (int j = 0; j < 3; j++) {
      float x = sr[tid + 256 * j];
      orow[tid + 256 * j] = x;
      mean[j] += x;
    }
  }
#pragma unroll
  for (int j = 0; j < 3; j++) mean[j] *= 0.125f;
  double ss = 0.0;
#pragma unroll
  for (int j = 0; j < 3; j++) ss += (double)mean[j] * mean[j];
  ss = blk_sum(ss, red);
  double inv = 1.0 / fmax(sqrt(ss), 1e-12);
  double dot = 0.0;
#pragma unroll
  for (int j = 0; j < 3; j++)
    dot += (double)tsrow[tid + 256 * j] * ((double)mean[j] * inv);
  dot = blk_sum(dot, red);
  const double p = dot / (double)0.07f;

  // NNCL logsumexp over columns c = tid
  const float* tc = TSn + (size_t)tid * D;
  double dot2 = 0.0;
  for (int e = 0; e < D; e += 4) {
    float4 t4 = *(const float4*)(tc + e);
    dot2 += (double)tsrow[e] * t4.x + (double)tsrow[e + 1] * t4.y +
            (double)tsrow[e + 2] * t4.z + (double)tsrow[e + 3] * t4.w;
  }
  const bool diag = (tid == b);
  double logit = dot2 / (double)0.07f;
  double m = blk_max(diag ? -1e300 : logit, red);
  m = fmax(m, p);
  double term = diag ? 0.0 : exp(logit - m);
  double ssum = blk_sum(term, red);
  ssum += exp(p - m);
  if (tid == 0) row_loss[b] = (log(ssum) + m) - p;
}

// ---------------- K5: finalize scalars --------------------------------------
__global__ __launch_bounds__(256) void finalize(const float* __restrict__ maxpart,
                                                const double* __restrict__ row_loss,
                                                float* __restrict__ d_out, int out_size,
                                                int V, int B, int vstride) {
  __shared__ double red[4];
  const int tid = threadIdx.x;
  double s1 = 0.0;
  for (int v = tid; v < V; v += 256) {
    float mx = fmaxf(fmaxf(maxpart[v], maxpart[vstride + v]),
                     fmaxf(maxpart[2 * vstride + v], maxpart[3 * vstride + v]));
    s1 += 2.0 - 2.0 * (double)mx;
  }
  s1 = blk_sum(s1, red);
  __syncthreads();
  double s2 = 0.0;
  for (int b = tid; b < B; b += 256) s2 += row_loss[b];
  s2 = blk_sum(s2, red);
  if (tid == 0) {
    d_out[out_size - 2] = (float)(s1 / ((double)V * (double)D));
    d_out[out_size - 1] = (float)(s2 / (double)B);
  }
}

// ---------------- host launcher ---------------------------------------------
extern "C" void kernel_launch(void* const* d_in, const int* in_sizes, int n_in,
                              void* d_out, int out_size, void* d_ws, size_t ws_size,
                              hipStream_t stream) {
  const float* TS  = (const float*)d_in[0];
  const float* W   = (const float*)d_in[1];
  const float* T   = (const float*)d_in[2];
  const float* SUP = (const float*)d_in[3];
  const int B = in_sizes[0] / D;   // 256
  const int V = in_sizes[1] / D;   // 50257
  const int U = in_sizes[2] / D;   // 1000
  const int Q = in_sizes[3] / D;   // 10000
  const int NT   = (U + 15) / 16;  // 63
  const int UPAD = NT * 16;        // 1008
  const int VPAD = (V + 63) & ~63; // 50304
  const int QPAD = (Q + 63) & ~63; // 10048
  const int NTB  = B / 16;         // 16
  const int nbT  = UPAD / 4;       // 252
  const int nbTS = B / 4;          // 64
  const int nbSUP = (Q + 3) / 4;   // 2500

  char* ws = (char*)d_ws;
  size_t off = 0;
  auto alloc = [&](size_t bytes) -> char* {
    char* p = ws + off;
    off = (off + bytes + 255) & ~(size_t)255;
    return p;
  };
  unsigned int* t8 = (unsigned int*)alloc((size_t)UPAD * D);  // fp8 bytes
  float*  maxpart= (float*) alloc((size_t)4 * VPAD * 4);
  float*  ts_n   = (float*) alloc((size_t)B * D * 4);
  bf16_t* ts_bf  = (bf16_t*)alloc((size_t)B * D * 2);
  float*  sup_n  = (float*) alloc((size_t)Q * D * 4);
  float*  simf   = (float*) alloc((size_t)B * QPAD * 4);
  double* rloss  = (double*)alloc((size_t)B * 8);
  (void)ws_size; (void)n_in;

  norm_all<<<nbT + nbTS + nbSUP, 256, 0, stream>>>(
      T, TS, SUP, t8, ts_n, ts_bf, sup_n, U, B, Q, nbT, nbTS);

  dim3 gms(VPAD / 64, 4);  // y = U-quarter
  maxsim_gemm<<<gms, 256, 0, stream>>>(W, (const unsigned char*)t8,
                                       maxpart, V, U, NT, VPAD);

  simf_gemm<<<QPAD / 64, 256, 0, stream>>>(sup_n, ts_bf, simf, Q, QPAD, NTB);
  topk_nncl<<<B, 256, 0, stream>>>(simf, sup_n, ts_n, (float*)d_out, rloss, Q, QPAD);
  finalize<<<1, 256, 0, stream>>>(maxpart, rloss, (float*)d_out, out_size, V, B, VPAD);
}

// Round 12
// 245.435 us; speedup vs baseline: 1.3564x; 1.2382x over previous
//
#include <hip/hip_runtime.h>
#include <hip/hip_bf16.h>
#include <math.h>

typedef __bf16 bf16_t;
typedef __bf16 bf16x8 __attribute__((ext_vector_type(8)));
typedef __bf16 bf16x4 __attribute__((ext_vector_type(4)));
typedef float  f32x4  __attribute__((ext_vector_type(4)));
typedef long   i64_t;
typedef unsigned long long u64_t;

#define D 768

// ---------------- block reduction helpers (blockDim == 256) ----------------
__device__ inline double blk_sum(double x, double* s) {
#pragma unroll
  for (int m = 32; m; m >>= 1) x += __shfl_xor(x, m);
  __syncthreads();
  if ((threadIdx.x & 63) == 0) s[threadIdx.x >> 6] = x;
  __syncthreads();
  return s[0] + s[1] + s[2] + s[3];
}

__device__ inline double blk_max(double x, double* s) {
#pragma unroll
  for (int m = 32; m; m >>= 1) x = fmax(x, __shfl_xor(x, m));
  __syncthreads();
  if ((threadIdx.x & 63) == 0) s[threadIdx.x >> 6] = x;
  __syncthreads();
  return fmax(fmax(s[0], s[1]), fmax(s[2], s[3]));
}

// ---------------- K1: fused normalize / quantize prepass --------------------
// Ranges: [0,nbT)          T   -> t8T  (k-major fp8, norm x16, [96][1024])
//         [nbT,+nbTS)      TS  -> ts_n (f32) + ts_bf (bf16)
//         [.. ,+nbSUP)     SUP -> sup_n (f32)
//         rest             W   -> w8t  (tile-transposed fp8 x16) + wscale
__global__ __launch_bounds__(256) void norm_all(
    const float* __restrict__ Tm, const float* __restrict__ TS,
    const float* __restrict__ SUP, const float* __restrict__ Wm,
    u64_t* __restrict__ t8T, u64_t* __restrict__ w8t,
    float* __restrict__ wscale, float* __restrict__ ts_n,
    bf16_t* __restrict__ ts_bf, float* __restrict__ sup_n,
    double* __restrict__ accd,
    int U, int V, int B, int Q, int nbT, int nbTS, int nbSUP) {
  const int wave = threadIdx.x >> 6, lane = threadIdx.x & 63;
  const int bid = blockIdx.x;
  if (bid == 0 && threadIdx.x == 0) accd[0] = 0.0;  // zero loss accumulator

  if (bid < nbT) {  // ---- T: norm + fp8(x16) + transpose to [96][1024] ----
    const int row = bid * 4 + wave;  // 0..1023
    double inv = 0.0;
    if (row < U) {
      const float4* s = (const float4*)(Tm + (size_t)row * D);
      double ss = 0.0;
#pragma unroll
      for (int j = 0; j < 3; j++) {
        float4 v = s[lane + 64 * j];
        ss += (double)v.x * v.x + (double)v.y * v.y +
              (double)v.z * v.z + (double)v.w * v.w;
      }
#pragma unroll
      for (int m = 32; m; m >>= 1) ss += __shfl_xor(ss, m);
      inv = 1.0 / fmax(sqrt(ss), 1e-12);
    }
    const float sc = (float)(inv * 16.0);
#pragma unroll
    for (int h = 0; h < 2; h++) {
      if (h == 1 && lane >= 32) continue;
      const int c = h * 64 + lane;  // chunk 0..95
      u64_t frag = 0ull;
      if (row < U) {
        const float* p = Tm + (size_t)row * D + c * 8;
        float4 x = *(const float4*)p;
        float4 y = *(const float4*)(p + 4);
        int lo = __builtin_amdgcn_cvt_pk_fp8_f32(x.x * sc, x.y * sc, 0, false);
        lo = __builtin_amdgcn_cvt_pk_fp8_f32(x.z * sc, x.w * sc, lo, true);
        int hi = __builtin_amdgcn_cvt_pk_fp8_f32(y.x * sc, y.y * sc, 0, false);
        hi = __builtin_amdgcn_cvt_pk_fp8_f32(y.z * sc, y.w * sc, hi, true);
        frag = ((u64_t)(unsigned)hi << 32) | (unsigned)lo;
      }
      t8T[(size_t)c * 1024 + row] = frag;
    }
    return;
  }

  if (bid < nbT + nbTS + nbSUP) {  // ---- TS / SUP: plain L2-normalize ----
    const float* src;
    int row;
    bool is_ts = false;
    if (bid < nbT + nbTS) { row = (bid - nbT) * 4 + wave; src = TS; is_ts = true; }
    else                  { row = (bid - nbT - nbTS) * 4 + wave; src = SUP;
                            if (row >= Q) return; }
    const float4* s = (const float4*)(src + (size_t)row * D);
    float4 v[3];
    double ss = 0.0;
#pragma unroll
    for (int j = 0; j < 3; j++) {
      v[j] = s[lane + 64 * j];
      ss += (double)v[j].x * v[j].x + (double)v[j].y * v[j].y +
            (double)v[j].z * v[j].z + (double)v[j].w * v[j].w;
    }
#pragma unroll
    for (int m = 32; m; m >>= 1) ss += __shfl_xor(ss, m);
    double inv = 1.0 / fmax(sqrt(ss), 1e-12);
    float4 o[3];
#pragma unroll
    for (int j = 0; j < 3; j++) {
      o[j].x = (float)((double)v[j].x * inv);
      o[j].y = (float)((double)v[j].y * inv);
      o[j].z = (float)((double)v[j].z * inv);
      o[j].w = (float)((double)v[j].w * inv);
    }
    float* dst = is_ts ? ts_n : sup_n;
    float* drow = dst + (size_t)row * D;
#pragma unroll
    for (int j = 0; j < 3; j++) ((float4*)drow)[lane + 64 * j] = o[j];
    if (is_ts) {
      bf16_t* brow = ts_bf + (size_t)row * D;
#pragma unroll
      for (int j = 0; j < 3; j++) {
        bf16x4 ob;
        ob[0] = (bf16_t)o[j].x; ob[1] = (bf16_t)o[j].y;
        ob[2] = (bf16_t)o[j].z; ob[3] = (bf16_t)o[j].w;
        *(bf16x4*)(brow + 4 * (lane + 64 * j)) = ob;
      }
    }
    return;
  }

  // ---- W: fp8(x16) tile-transposed + inverse norm (scale-invariant) ------
  const int v = (bid - nbT - nbTS - nbSUP) * 4 + wave;  // < VPAD by grid
  u64_t* tile = w8t + (size_t)(v >> 4) * 1536;          // 96 chunks x 16 rows
  if (v >= V) {
#pragma unroll
    for (int h = 0; h < 2; h++) {
      const int c = h * 64 + lane;
      if (c < 96) tile[c * 16 + (v & 15)] = 0ull;
    }
    if (lane == 0) wscale[v] = 0.f;
    return;
  }
  const float* Wp = Wm + (size_t)v * D;
  const float4* sp = (const float4*)Wp;
  float ssf = 0.f;
#pragma unroll
  for (int j = 0; j < 3; j++) {
    float4 x = sp[lane + 64 * j];
    ssf += x.x * x.x + x.y * x.y + x.z * x.z + x.w * x.w;
  }
#pragma unroll
  for (int m = 32; m; m >>= 1) ssf += __shfl_xor(ssf, m);
  if (lane == 0)
    wscale[v] = (float)(1.0 / (256.0 * fmax(sqrt((double)ssf), 1e-12)));
#pragma unroll
  for (int h = 0; h < 2; h++) {
    const int c = h * 64 + lane;
    if (c >= 96) continue;
    const float* p = Wp + c * 8;
    float4 x = *(const float4*)p;
    float4 y = *(const float4*)(p + 4);
    int lo = __builtin_amdgcn_cvt_pk_fp8_f32(x.x * 16.f, x.y * 16.f, 0, false);
    lo = __builtin_amdgcn_cvt_pk_fp8_f32(x.z * 16.f, x.w * 16.f, lo, true);
    int hi = __builtin_amdgcn_cvt_pk_fp8_f32(y.x * 16.f, y.y * 16.f, 0, false);
    hi = __builtin_amdgcn_cvt_pk_fp8_f32(y.z * 16.f, y.w * 16.f, hi, true);
    tile[c * 16 + (v & 15)] = ((u64_t)(unsigned)hi << 32) | (unsigned)lo;
  }
}

// ---------------- K2: max-sim GEMM v12 (persistent-T, barrier-free loop) ---
// Block = proto-group g (64 protos, 4 subtiles of 16) resident in LDS,
// loaded ONCE (single barrier). Each wave streams 4 W-tiles (16 rows) as
// register A-fragments (one coalesced 512B load per fragment from the
// tile-transposed w8t) and runs 4 independent MFMA chains (one per proto
// subtile) sharing each A fragment. No barriers, no LDS writes in the loop.
// Raw (x256-scaled) row-max written to maxpart[g][v]; normalized later.
__global__ __launch_bounds__(256) void maxsim_gemm(
    const u64_t* __restrict__ W8T, const u64_t* __restrict__ T8T,
    float* __restrict__ maxpart, int U, int vstride) {
  __shared__ u64_t bt[4 * 96 * 16];  // 48 KB: [subtile][chunk][proto]
  const int tid  = threadIdx.x;
  const int lane = tid & 63;
  const int r    = lane & 15;   // proto col (C) / W row (A)
  const int ks   = lane >> 4;   // k-slice 0..3
  const int g    = blockIdx.x;  // proto group 0..15

  // stage 4 proto subtiles once (3072 x 16B chunks)
  {
    const int pb = g * 64;
#pragma unroll
    for (int j = 0; j < 12; j++) {
      const int m = j * 256 + tid;        // 0..3071
      const int s = m / 768;
      const int rem = m - s * 768;
      const int c = rem >> 3, h = rem & 7;
      ulonglong2 val = *(const ulonglong2*)(T8T + (size_t)c * 1024 + pb + s * 16 + h * 2);
      *(ulonglong2*)(bt + s * 1536 + c * 16 + h * 2) = val;
    }
  }
  __syncthreads();

  bool msk[4];
#pragma unroll
  for (int s = 0; s < 4; s++) msk[s] = (g * 64 + s * 16 + r) < U;

  const int wv = tid >> 6;
#pragma unroll
  for (int wt = 0; wt < 4; wt++) {
    const int v0 = blockIdx.y * 256 + wv * 64 + wt * 16;
    const u64_t* ap = W8T + (size_t)(v0 >> 4) * 1536;
    u64_t a[24];
#pragma unroll
    for (int kk = 0; kk < 24; kk++) a[kk] = ap[kk * 64 + lane];
    f32x4 ac0 = {0.f,0.f,0.f,0.f}, ac1 = {0.f,0.f,0.f,0.f};
    f32x4 ac2 = {0.f,0.f,0.f,0.f}, ac3 = {0.f,0.f,0.f,0.f};
#pragma unroll
    for (int kk = 0; kk < 24; kk++) {
      const int ci = kk * 64 + lane;
      ac0 = __builtin_amdgcn_mfma_f32_16x16x32_fp8_fp8(
          (i64_t)a[kk], (i64_t)bt[ci],            ac0, 0, 0, 0);
      ac1 = __builtin_amdgcn_mfma_f32_16x16x32_fp8_fp8(
          (i64_t)a[kk], (i64_t)bt[1536 + ci],     ac1, 0, 0, 0);
      ac2 = __builtin_amdgcn_mfma_f32_16x16x32_fp8_fp8(
          (i64_t)a[kk], (i64_t)bt[2 * 1536 + ci], ac2, 0, 0, 0);
      ac3 = __builtin_amdgcn_mfma_f32_16x16x32_fp8_fp8(
          (i64_t)a[kk], (i64_t)bt[3 * 1536 + ci], ac3, 0, 0, 0);
    }
    // C layout: col = lane&15 (proto), row = ks*4+j (W row)
    f32x4 mx = {-1e30f, -1e30f, -1e30f, -1e30f};
#pragma unroll
    for (int j = 0; j < 4; j++) {
      if (msk[0]) mx[j] = fmaxf(mx[j], ac0[j]);
      if (msk[1]) mx[j] = fmaxf(mx[j], ac1[j]);
      if (msk[2]) mx[j] = fmaxf(mx[j], ac2[j]);
      if (msk[3]) mx[j] = fmaxf(mx[j], ac3[j]);
    }
#pragma unroll
    for (int m = 1; m < 16; m <<= 1) {
#pragma unroll
      for (int j = 0; j < 4; j++) mx[j] = fmaxf(mx[j], __shfl_xor(mx[j], m));
    }
    if (r == 0) {
#pragma unroll
      for (int j = 0; j < 4; j++)
        maxpart[(size_t)g * vstride + v0 + ks * 4 + j] = mx[j];
    }
  }
}

// ---------------- K3: approx sim GEMM (bf16 MFMA) ---------------------------
#define LDSROW 776  // 768 + 8 pad (bf16 units)

__global__ __launch_bounds__(256) void simf_gemm(const float* __restrict__ SUPn,
                                                 const bf16_t* __restrict__ TSb,
                                                 float* __restrict__ sim,
                                                 int Q, int ld, int NTB) {
  __shared__ __align__(16) bf16_t lds[2][16 * LDSROW];
  const int tid  = threadIdx.x;
  const int lane = tid & 63;
  const int rowbase = blockIdx.x * 64 + (tid >> 6) * 16;
  const int arow_i  = rowbase + (lane & 15);

  bf16x8 a[24];
  if (arow_i < Q) {
    const float* ar = SUPn + (size_t)arow_i * D + ((lane >> 4) * 8);
#pragma unroll
    for (int kk = 0; kk < 24; kk++) {
      float4 x = *(const float4*)(ar + kk * 32);
      float4 y = *(const float4*)(ar + kk * 32 + 4);
      bf16x8 f;
      f[0] = (bf16_t)x.x; f[1] = (bf16_t)x.y; f[2] = (bf16_t)x.z; f[3] = (bf16_t)x.w;
      f[4] = (bf16_t)y.x; f[5] = (bf16_t)y.y; f[6] = (bf16_t)y.z; f[7] = (bf16_t)y.w;
      a[kk] = f;
    }
  } else {
#pragma unroll
    for (int kk = 0; kk < 24; kk++) {
      bf16x8 f;
#pragma unroll
      for (int e = 0; e < 8; e++) f[e] = (bf16_t)0.f;
      a[kk] = f;
    }
  }

  auto stage = [&](int buf, int nt) {
    const ulonglong2* src = (const ulonglong2*)(TSb + (size_t)nt * 16 * D);
#pragma unroll
    for (int j = 0; j < 6; j++) {
      int c = tid + j * 256;
      int rr = c / 96, w = c % 96;
      *(ulonglong2*)&lds[buf][rr * LDSROW + w * 8] = src[c];
    }
  };

  stage(0, 0);
  for (int nt = 0; nt < NTB; nt++) {
    __syncthreads();
    if (nt + 1 < NTB) stage((nt + 1) & 1, nt + 1);
    f32x4 acc = {0.f, 0.f, 0.f, 0.f};
    const bf16_t* brow = &lds[nt & 1][(lane & 15) * LDSROW + ((lane >> 4) * 8)];
#pragma unroll
    for (int kk = 0; kk < 24; kk++) {
      bf16x8 b = *(const bf16x8*)(brow + kk * 32);
      acc = __builtin_amdgcn_mfma_f32_16x16x32_bf16(a[kk], b, acc, 0, 0, 0);
    }
    const int bcol = nt * 16 + (lane & 15);
    const int q0   = rowbase + ((lane >> 4) << 2);
    float* dst = sim + (size_t)bcol * ld + q0;
    if (q0 + 3 < Q) {
      *(f32x4*)dst = acc;
    } else {
#pragma unroll
      for (int j = 0; j < 4; j++)
        if (q0 + j < Q) dst[j] = acc[j];
    }
  }
}

// ---------------- K4: top-16 + f64 rescore + gather + pos + NNCL -----------
__device__ inline unsigned long long pack_key(float v, int q) {
  unsigned u = __float_as_uint(v);
  u = (u & 0x80000000u) ? ~u : (u | 0x80000000u);  // order-preserving map
  return ((unsigned long long)u << 32) | (unsigned)(0xFFFFFFFFu - (unsigned)q);
}

__global__ __launch_bounds__(256) void topk_nncl(const float* __restrict__ sim,
                                                 const float* __restrict__ SUPn,
                                                 const float* __restrict__ TSn,
                                                 float* __restrict__ out,
                                                 double* __restrict__ row_loss,
                                                 int Q, int ld) {
  __shared__ unsigned long long sk[256][16];
  __shared__ float tsrow[D];
  __shared__ double sval[16];
  __shared__ int    sidx[16];
  __shared__ double red[4];
  const int b = blockIdx.x, tid = threadIdx.x;
#pragma unroll
  for (int j = 0; j < 3; j++) tsrow[tid + 256 * j] = TSn[(size_t)b * D + tid + 256 * j];

  const float* row = sim + (size_t)b * ld;
  unsigned long long best[16];
#pragma unroll
  for (int k = 0; k < 16; k++) best[k] = 0ull;
  for (int q = tid; q < Q; q += 256) {
    unsigned long long key = pack_key(row[q], q);
    if (key > best[15]) {
      best[15] = key;
      for (int k = 15; k > 0; k--) {
        if (best[k] > best[k - 1]) {
          unsigned long long t = best[k]; best[k] = best[k - 1]; best[k - 1] = t;
        } else break;
      }
    }
  }
#pragma unroll
  for (int k = 0; k < 16; k++) sk[tid][k] = best[k];
  for (int stride = 128; stride >= 1; stride >>= 1) {
    __syncthreads();
    if (tid < stride) {
      unsigned long long outk[16];
      int pa = 0, pb = 0;
#pragma unroll
      for (int k = 0; k < 16; k++) {
        unsigned long long va = sk[tid][pa], vb = sk[tid + stride][pb];
        if (va >= vb) { outk[k] = va; pa++; }
        else          { outk[k] = vb; pb++; }
      }
#pragma unroll
      for (int k = 0; k < 16; k++) sk[tid][k] = outk[k];
    }
  }
  __syncthreads();

  // exact f64 rescore of the 16 candidates (1 wave each, 4 rounds)
  const int lane = tid & 63, w = tid >> 6;
  for (int c = w; c < 16; c += 4) {
    int q = (int)(0xFFFFFFFFu - (unsigned)(sk[0][c] & 0xFFFFFFFFull));
    const float* sr = SUPn + (size_t)q * D;
    double dot = 0.0;
#pragma unroll
    for (int i = 0; i < 12; i++)
      dot += (double)sr[lane + 64 * i] * (double)tsrow[lane + 64 * i];
#pragma unroll
    for (int m = 32; m; m >>= 1) dot += __shfl_xor(dot, m);
    if (lane == 0) { sval[c] = dot; sidx[c] = q; }
  }
  __syncthreads();
  if (tid == 0) {
    for (int i = 1; i < 16; i++) {
      double v = sval[i]; int ix = sidx[i];
      int j = i - 1;
      while (j >= 0 && (sval[j] < v || (sval[j] == v && sidx[j] > ix))) {
        sval[j + 1] = sval[j]; sidx[j + 1] = sidx[j]; j--;
      }
      sval[j + 1] = v; sidx[j + 1] = ix;
    }
  }
  __syncthreads();

  // gather top-8 rows to output + positive mean + pos_sim
  float mean[3] = {0.f, 0.f, 0.f};
#pragma unroll
  for (int k = 0; k < 8; k++) {
    const float* sr = SUPn + (size_t)sidx[k] * D;
    float* orow = out + ((size_t)b * 8 + k) * D;
#pragma unroll
    for (int j = 0; j < 3; j++) {
      float x = sr[tid + 256 * j];
      orow[tid + 256 * j] = x;
      mean[j] += x;
    }
  }
#pragma unroll
  for (int j = 0; j < 3; j++) mean[j] *= 0.125f;
  double ss = 0.0;
#pragma unroll
  for (int j = 0; j < 3; j++) ss += (double)mean[j] * mean[j];
  ss = blk_sum(ss, red);
  double inv = 1.0 / fmax(sqrt(ss), 1e-12);
  double dot = 0.0;
#pragma unroll
  for (int j = 0; j < 3; j++)
    dot += (double)tsrow[tid + 256 * j] * ((double)mean[j] * inv);
  dot = blk_sum(dot, red);
  const double p = dot / (double)0.07f;

  // NNCL logsumexp over columns c = tid
  const float* tc = TSn + (size_t)tid * D;
  double dot2 = 0.0;
  for (int e = 0; e < D; e += 4) {
    float4 t4 = *(const float4*)(tc + e);
    dot2 += (double)tsrow[e] * t4.x + (double)tsrow[e + 1] * t4.y +
            (double)tsrow[e + 2] * t4.z + (double)tsrow[e + 3] * t4.w;
  }
  const bool diag = (tid == b);
  double logit = dot2 / (double)0.07f;
  double m = blk_max(diag ? -1e300 : logit, red);
  m = fmax(m, p);
  double term = diag ? 0.0 : exp(logit - m);
  double ssum = blk_sum(term, red);
  ssum += exp(p - m);
  if (tid == 0) row_loss[b] = (log(ssum) + m) - p;
}

// ---------------- K5: combine proto maxes -> partial loss sums --------------
__global__ __launch_bounds__(256) void reduce_proto(
    const float* __restrict__ maxpart, const float* __restrict__ wscale,
    double* __restrict__ accd, int V, int vstride) {
  __shared__ double red[4];
  const int v = blockIdx.x * 256 + threadIdx.x;
  double s = 0.0;
  if (v < V) {
    float mx = -1e30f;
#pragma unroll
    for (int g = 0; g < 16; g++)
      mx = fmaxf(mx, maxpart[(size_t)g * vstride + v]);
    s = 2.0 - 2.0 * (double)mx * (double)wscale[v];
  }
  s = blk_sum(s, red);
  if (threadIdx.x == 0) atomicAdd(accd, s);
}

// ---------------- K6: finalize scalars --------------------------------------
__global__ __launch_bounds__(256) void finalize(const double* __restrict__ accd,
                                                const double* __restrict__ row_loss,
                                                float* __restrict__ d_out, int out_size,
                                                int V, int B) {
  __shared__ double red[4];
  const int tid = threadIdx.x;
  double s2 = 0.0;
  for (int b = tid; b < B; b += 256) s2 += row_loss[b];
  s2 = blk_sum(s2, red);
  if (tid == 0) {
    d_out[out_size - 2] = (float)(accd[0] / ((double)V * (double)D));
    d_out[out_size - 1] = (float)(s2 / (double)B);
  }
}

// ---------------- host launcher ---------------------------------------------
extern "C" void kernel_launch(void* const* d_in, const int* in_sizes, int n_in,
                              void* d_out, int out_size, void* d_ws, size_t ws_size,
                              hipStream_t stream) {
  const float* TS  = (const float*)d_in[0];
  const float* W   = (const float*)d_in[1];
  const float* T   = (const float*)d_in[2];
  const float* SUP = (const float*)d_in[3];
  const int B = in_sizes[0] / D;   // 256
  const int V = in_sizes[1] / D;   // 50257
  const int U = in_sizes[2] / D;   // 1000
  const int Q = in_sizes[3] / D;   // 10000
  const int VPAD = (V + 255) & ~255; // 50432
  const int QPAD = (Q + 63) & ~63; // 10048
  const int NTB  = B / 16;         // 16
  const int nbT  = 1024 / 4;       // 256
  const int nbTS = B / 4;          // 64
  const int nbSUP = (Q + 3) / 4;   // 2500
  const int nbW  = VPAD / 4;       // 12608

  char* ws = (char*)d_ws;
  size_t off = 0;
  auto alloc = [&](size_t bytes) -> char* {
    char* p = ws + off;
    off = (off + bytes + 255) & ~(size_t)255;
    return p;
  };
  u64_t*  t8T    = (u64_t*) alloc((size_t)96 * 1024 * 8);       // 786 KB
  u64_t*  w8t    = (u64_t*) alloc((size_t)(VPAD / 16) * 1536 * 8); // 38.7 MB
  float*  wscale = (float*) alloc((size_t)VPAD * 4);
  float*  maxpart= (float*) alloc((size_t)16 * VPAD * 4);       // 3.2 MB
  float*  ts_n   = (float*) alloc((size_t)B * D * 4);
  bf16_t* ts_bf  = (bf16_t*)alloc((size_t)B * D * 2);
  float*  sup_n  = (float*) alloc((size_t)Q * D * 4);
  float*  simf   = (float*) alloc((size_t)B * QPAD * 4);
  double* rloss  = (double*)alloc((size_t)B * 8);
  double* accd   = (double*)alloc(8);
  (void)ws_size; (void)n_in;

  norm_all<<<nbT + nbTS + nbSUP + nbW, 256, 0, stream>>>(
      T, TS, SUP, W, t8T, w8t, wscale, ts_n, ts_bf, sup_n, accd,
      U, V, B, Q, nbT, nbTS, nbSUP);

  dim3 gms(16, VPAD / 256);  // x = proto-group, y = W-range (256 rows)
  maxsim_gemm<<<gms, 256, 0, stream>>>(w8t, t8T, maxpart, U, VPAD);

  simf_gemm<<<QPAD / 64, 256, 0, stream>>>(sup_n, ts_bf, simf, Q, QPAD, NTB);
  topk_nncl<<<B, 256, 0, stream>>>(simf, sup_n, ts_n, (float*)d_out, rloss, Q, QPAD);
  reduce_proto<<<VPAD / 256, 256, 0, stream>>>(maxpart, wscale, accd, V, VPAD);
  finalize<<<1, 256, 0, stream>>>(accd, rloss, (float*)d_out, out_size, V, B);
}

// Round 13
// 222.931 us; speedup vs baseline: 1.4933x; 1.1009x over previous
//
#include <hip/hip_runtime.h>
#include <hip/hip_bf16.h>
#include <math.h>

typedef __bf16 bf16_t;
typedef __bf16 bf16x8 __attribute__((ext_vector_type(8)));
typedef __bf16 bf16x4 __attribute__((ext_vector_type(4)));
typedef float  f32x4  __attribute__((ext_vector_type(4)));
typedef long   i64_t;
typedef unsigned long long u64_t;

#define D 768

// ---------------- block reduction helpers (blockDim == 256) ----------------
__device__ inline double blk_sum(double x, double* s) {
#pragma unroll
  for (int m = 32; m; m >>= 1) x += __shfl_xor(x, m);
  __syncthreads();
  if ((threadIdx.x & 63) == 0) s[threadIdx.x >> 6] = x;
  __syncthreads();
  return s[0] + s[1] + s[2] + s[3];
}

__device__ inline double blk_max(double x, double* s) {
#pragma unroll
  for (int m = 32; m; m >>= 1) x = fmax(x, __shfl_xor(x, m));
  __syncthreads();
  if ((threadIdx.x & 63) == 0) s[threadIdx.x >> 6] = x;
  __syncthreads();
  return fmax(fmax(s[0], s[1]), fmax(s[2], s[3]));
}

// ---------------- K1: fused normalize / quantize prepass --------------------
// Ranges: [0,nbT)          T   -> t8T  (k-major fp8, norm x16, [96][1024])
//         [nbT,+nbTS)      TS  -> ts_n (f32) + ts_bf (bf16)
//         [.. ,+nbSUP)     SUP -> sup_n (f32)
//         rest             W   -> w8t (tile-transposed fp8 x16, COALESCED
//                                 read+write: wave=16-row tile, lane=(cs,r),
//                                 write idx j*64+lane) + wscale
__global__ __launch_bounds__(256) void norm_all(
    const float* __restrict__ Tm, const float* __restrict__ TS,
    const float* __restrict__ SUP, const float* __restrict__ Wm,
    u64_t* __restrict__ t8T, u64_t* __restrict__ w8t,
    float* __restrict__ wscale, float* __restrict__ ts_n,
    bf16_t* __restrict__ ts_bf, float* __restrict__ sup_n,
    double* __restrict__ accd,
    int U, int V, int B, int Q, int nbT, int nbTS, int nbSUP) {
  const int wave = threadIdx.x >> 6, lane = threadIdx.x & 63;
  const int bid = blockIdx.x;
  if (bid == 0 && threadIdx.x == 0) accd[0] = 0.0;  // zero loss accumulator

  if (bid < nbT) {  // ---- T: norm + fp8(x16) + transpose to [96][1024] ----
    const int row = bid * 4 + wave;  // 0..1023
    double inv = 0.0;
    if (row < U) {
      const float4* s = (const float4*)(Tm + (size_t)row * D);
      double ss = 0.0;
#pragma unroll
      for (int j = 0; j < 3; j++) {
        float4 v = s[lane + 64 * j];
        ss += (double)v.x * v.x + (double)v.y * v.y +
              (double)v.z * v.z + (double)v.w * v.w;
      }
#pragma unroll
      for (int m = 32; m; m >>= 1) ss += __shfl_xor(ss, m);
      inv = 1.0 / fmax(sqrt(ss), 1e-12);
    }
    const float sc = (float)(inv * 16.0);
#pragma unroll
    for (int h = 0; h < 2; h++) {
      if (h == 1 && lane >= 32) continue;
      const int c = h * 64 + lane;  // chunk 0..95
      u64_t frag = 0ull;
      if (row < U) {
        const float* p = Tm + (size_t)row * D + c * 8;
        float4 x = *(const float4*)p;
        float4 y = *(const float4*)(p + 4);
        int lo = __builtin_amdgcn_cvt_pk_fp8_f32(x.x * sc, x.y * sc, 0, false);
        lo = __builtin_amdgcn_cvt_pk_fp8_f32(x.z * sc, x.w * sc, lo, true);
        int hi = __builtin_amdgcn_cvt_pk_fp8_f32(y.x * sc, y.y * sc, 0, false);
        hi = __builtin_amdgcn_cvt_pk_fp8_f32(y.z * sc, y.w * sc, hi, true);
        frag = ((u64_t)(unsigned)hi << 32) | (unsigned)lo;
      }
      t8T[(size_t)c * 1024 + row] = frag;
    }
    return;
  }

  if (bid < nbT + nbTS + nbSUP) {  // ---- TS / SUP: plain L2-normalize ----
    const float* src;
    int row;
    bool is_ts = false;
    if (bid < nbT + nbTS) { row = (bid - nbT) * 4 + wave; src = TS; is_ts = true; }
    else                  { row = (bid - nbT - nbTS) * 4 + wave; src = SUP;
                            if (row >= Q) return; }
    const float4* s = (const float4*)(src + (size_t)row * D);
    float4 v[3];
    double ss = 0.0;
#pragma unroll
    for (int j = 0; j < 3; j++) {
      v[j] = s[lane + 64 * j];
      ss += (double)v[j].x * v[j].x + (double)v[j].y * v[j].y +
            (double)v[j].z * v[j].z + (double)v[j].w * v[j].w;
    }
#pragma unroll
    for (int m = 32; m; m >>= 1) ss += __shfl_xor(ss, m);
    double inv = 1.0 / fmax(sqrt(ss), 1e-12);
    float4 o[3];
#pragma unroll
    for (int j = 0; j < 3; j++) {
      o[j].x = (float)((double)v[j].x * inv);
      o[j].y = (float)((double)v[j].y * inv);
      o[j].z = (float)((double)v[j].z * inv);
      o[j].w = (float)((double)v[j].w * inv);
    }
    float* dst = is_ts ? ts_n : sup_n;
    float* drow = dst + (size_t)row * D;
#pragma unroll
    for (int j = 0; j < 3; j++) ((float4*)drow)[lane + 64 * j] = o[j];
    if (is_ts) {
      bf16_t* brow = ts_bf + (size_t)row * D;
#pragma unroll
      for (int j = 0; j < 3; j++) {
        bf16x4 ob;
        ob[0] = (bf16_t)o[j].x; ob[1] = (bf16_t)o[j].y;
        ob[2] = (bf16_t)o[j].z; ob[3] = (bf16_t)o[j].w;
        *(bf16x4*)(brow + 4 * (lane + 64 * j)) = ob;
      }
    }
    return;
  }

  // ---- W: fp8(x16) tile-transposed, single coalesced read+write ----------
  // Wave handles one 16-row tile; lane = (cs = lane>>4, r = lane&15).
  // Iter j: read row r chunk c=j*4+cs (32B; 4 lanes/row -> 128B segments),
  // write tile[j*64+lane] (512B coalesced; idx == c*16 + r).
  {
    const int v0 = (bid - nbT - nbTS - nbSUP) * 64 + wave * 16;  // tile base
    const int r  = lane & 15;
    const int cs = lane >> 4;
    const int v  = v0 + r;
    const bool valid = v < V;
    const float* Wp = Wm + (size_t)v * D;
    u64_t* tile = w8t + (size_t)(v0 >> 4) * 1536;
    float ssf = 0.f;
#pragma unroll
    for (int j = 0; j < 24; j++) {
      u64_t frag = 0ull;
      if (valid) {
        const float* p = Wp + (j * 4 + cs) * 8;
        float4 x = *(const float4*)p;
        float4 y = *(const float4*)(p + 4);
        ssf += x.x * x.x + x.y * x.y + x.z * x.z + x.w * x.w +
               y.x * y.x + y.y * y.y + y.z * y.z + y.w * y.w;
        int lo = __builtin_amdgcn_cvt_pk_fp8_f32(x.x * 16.f, x.y * 16.f, 0, false);
        lo = __builtin_amdgcn_cvt_pk_fp8_f32(x.z * 16.f, x.w * 16.f, lo, true);
        int hi = __builtin_amdgcn_cvt_pk_fp8_f32(y.x * 16.f, y.y * 16.f, 0, false);
        hi = __builtin_amdgcn_cvt_pk_fp8_f32(y.z * 16.f, y.w * 16.f, hi, true);
        frag = ((u64_t)(unsigned)hi << 32) | (unsigned)lo;
      }
      tile[j * 64 + lane] = frag;
    }
    // row-norm: reduce over the 4 lanes sharing r (xor 16, 32)
    ssf += __shfl_xor(ssf, 16);
    ssf += __shfl_xor(ssf, 32);
    if (cs == 0)
      wscale[v0 + r] = valid
          ? (float)(1.0 / (256.0 * fmax(sqrt((double)ssf), 1e-12)))
          : 0.f;
  }
}

// ---------------- K2: max-sim GEMM v12 (persistent-T, barrier-free loop) ---
__global__ __launch_bounds__(256) void maxsim_gemm(
    const u64_t* __restrict__ W8T, const u64_t* __restrict__ T8T,
    float* __restrict__ maxpart, int U, int vstride) {
  __shared__ u64_t bt[4 * 96 * 16];  // 48 KB: [subtile][chunk][proto]
  const int tid  = threadIdx.x;
  const int lane = tid & 63;
  const int r    = lane & 15;   // proto col (C) / W row (A)
  const int ks   = lane >> 4;   // k-slice 0..3
  const int g    = blockIdx.x;  // proto group 0..15

  // stage 4 proto subtiles once (3072 x 16B chunks)
  {
    const int pb = g * 64;
#pragma unroll
    for (int j = 0; j < 12; j++) {
      const int m = j * 256 + tid;        // 0..3071
      const int s = m / 768;
      const int rem = m - s * 768;
      const int c = rem >> 3, h = rem & 7;
      ulonglong2 val = *(const ulonglong2*)(T8T + (size_t)c * 1024 + pb + s * 16 + h * 2);
      *(ulonglong2*)(bt + s * 1536 + c * 16 + h * 2) = val;
    }
  }
  __syncthreads();

  bool msk[4];
#pragma unroll
  for (int s = 0; s < 4; s++) msk[s] = (g * 64 + s * 16 + r) < U;

  const int wv = tid >> 6;
#pragma unroll
  for (int wt = 0; wt < 4; wt++) {
    const int v0 = blockIdx.y * 256 + wv * 64 + wt * 16;
    const u64_t* ap = W8T + (size_t)(v0 >> 4) * 1536;
    u64_t a[24];
#pragma unroll
    for (int kk = 0; kk < 24; kk++) a[kk] = ap[kk * 64 + lane];
    f32x4 ac0 = {0.f,0.f,0.f,0.f}, ac1 = {0.f,0.f,0.f,0.f};
    f32x4 ac2 = {0.f,0.f,0.f,0.f}, ac3 = {0.f,0.f,0.f,0.f};
#pragma unroll
    for (int kk = 0; kk < 24; kk++) {
      const int ci = kk * 64 + lane;
      ac0 = __builtin_amdgcn_mfma_f32_16x16x32_fp8_fp8(
          (i64_t)a[kk], (i64_t)bt[ci],            ac0, 0, 0, 0);
      ac1 = __builtin_amdgcn_mfma_f32_16x16x32_fp8_fp8(
          (i64_t)a[kk], (i64_t)bt[1536 + ci],     ac1, 0, 0, 0);
      ac2 = __builtin_amdgcn_mfma_f32_16x16x32_fp8_fp8(
          (i64_t)a[kk], (i64_t)bt[2 * 1536 + ci], ac2, 0, 0, 0);
      ac3 = __builtin_amdgcn_mfma_f32_16x16x32_fp8_fp8(
          (i64_t)a[kk], (i64_t)bt[3 * 1536 + ci], ac3, 0, 0, 0);
    }
    // C layout: col = lane&15 (proto), row = ks*4+j (W row)
    f32x4 mx = {-1e30f, -1e30f, -1e30f, -1e30f};
#pragma unroll
    for (int j = 0; j < 4; j++) {
      if (msk[0]) mx[j] = fmaxf(mx[j], ac0[j]);
      if (msk[1]) mx[j] = fmaxf(mx[j], ac1[j]);
      if (msk[2]) mx[j] = fmaxf(mx[j], ac2[j]);
      if (msk[3]) mx[j] = fmaxf(mx[j], ac3[j]);
    }
#pragma unroll
    for (int m = 1; m < 16; m <<= 1) {
#pragma unroll
      for (int j = 0; j < 4; j++) mx[j] = fmaxf(mx[j], __shfl_xor(mx[j], m));
    }
    if (r == 0) {
#pragma unroll
      for (int j = 0; j < 4; j++)
        maxpart[(size_t)g * vstride + v0 + ks * 4 + j] = mx[j];
    }
  }
}

// ---------------- K3: approx sim GEMM (bf16 MFMA) ---------------------------
#define LDSROW 776  // 768 + 8 pad (bf16 units)

__global__ __launch_bounds__(256) void simf_gemm(const float* __restrict__ SUPn,
                                                 const bf16_t* __restrict__ TSb,
                                                 float* __restrict__ sim,
                                                 int Q, int ld, int NTB) {
  __shared__ __align__(16) bf16_t lds[2][16 * LDSROW];
  const int tid  = threadIdx.x;
  const int lane = tid & 63;
  const int rowbase = blockIdx.x * 64 + (tid >> 6) * 16;
  const int arow_i  = rowbase + (lane & 15);

  bf16x8 a[24];
  if (arow_i < Q) {
    const float* ar = SUPn + (size_t)arow_i * D + ((lane >> 4) * 8);
#pragma unroll
    for (int kk = 0; kk < 24; kk++) {
      float4 x = *(const float4*)(ar + kk * 32);
      float4 y = *(const float4*)(ar + kk * 32 + 4);
      bf16x8 f;
      f[0] = (bf16_t)x.x; f[1] = (bf16_t)x.y; f[2] = (bf16_t)x.z; f[3] = (bf16_t)x.w;
      f[4] = (bf16_t)y.x; f[5] = (bf16_t)y.y; f[6] = (bf16_t)y.z; f[7] = (bf16_t)y.w;
      a[kk] = f;
    }
  } else {
#pragma unroll
    for (int kk = 0; kk < 24; kk++) {
      bf16x8 f;
#pragma unroll
      for (int e = 0; e < 8; e++) f[e] = (bf16_t)0.f;
      a[kk] = f;
    }
  }

  auto stage = [&](int buf, int nt) {
    const ulonglong2* src = (const ulonglong2*)(TSb + (size_t)nt * 16 * D);
#pragma unroll
    for (int j = 0; j < 6; j++) {
      int c = tid + j * 256;
      int rr = c / 96, w = c % 96;
      *(ulonglong2*)&lds[buf][rr * LDSROW + w * 8] = src[c];
    }
  };

  stage(0, 0);
  for (int nt = 0; nt < NTB; nt++) {
    __syncthreads();
    if (nt + 1 < NTB) stage((nt + 1) & 1, nt + 1);
    f32x4 acc = {0.f, 0.f, 0.f, 0.f};
    const bf16_t* brow = &lds[nt & 1][(lane & 15) * LDSROW + ((lane >> 4) * 8)];
#pragma unroll
    for (int kk = 0; kk < 24; kk++) {
      bf16x8 b = *(const bf16x8*)(brow + kk * 32);
      acc = __builtin_amdgcn_mfma_f32_16x16x32_bf16(a[kk], b, acc, 0, 0, 0);
    }
    const int bcol = nt * 16 + (lane & 15);
    const int q0   = rowbase + ((lane >> 4) << 2);
    float* dst = sim + (size_t)bcol * ld + q0;
    if (q0 + 3 < Q) {
      *(f32x4*)dst = acc;
    } else {
#pragma unroll
      for (int j = 0; j < 4; j++)
        if (q0 + j < Q) dst[j] = acc[j];
    }
  }
}

// ---------------- K4: top-16 + f64 rescore + gather + pos + NNCL -----------
__device__ inline unsigned long long pack_key(float v, int q) {
  unsigned u = __float_as_uint(v);
  u = (u & 0x80000000u) ? ~u : (u | 0x80000000u);  // order-preserving map
  return ((unsigned long long)u << 32) | (unsigned)(0xFFFFFFFFu - (unsigned)q);
}

__global__ __launch_bounds__(256) void topk_nncl(const float* __restrict__ sim,
                                                 const float* __restrict__ SUPn,
                                                 const float* __restrict__ TSn,
                                                 float* __restrict__ out,
                                                 double* __restrict__ row_loss,
                                                 int Q, int ld) {
  __shared__ unsigned long long sk[256][16];
  __shared__ float tsrow[D];
  __shared__ double sval[16];
  __shared__ int    sidx[16];
  __shared__ double red[4];
  const int b = blockIdx.x, tid = threadIdx.x;
#pragma unroll
  for (int j = 0; j < 3; j++) tsrow[tid + 256 * j] = TSn[(size_t)b * D + tid + 256 * j];

  const float* row = sim + (size_t)b * ld;
  unsigned long long best[16];
#pragma unroll
  for (int k = 0; k < 16; k++) best[k] = 0ull;
  for (int q = tid; q < Q; q += 256) {
    unsigned long long key = pack_key(row[q], q);
    if (key > best[15]) {
      best[15] = key;
      for (int k = 15; k > 0; k--) {
        if (best[k] > best[k - 1]) {
          unsigned long long t = best[k]; best[k] = best[k - 1]; best[k - 1] = t;
        } else break;
      }
    }
  }
#pragma unroll
  for (int k = 0; k < 16; k++) sk[tid][k] = best[k];
  for (int stride = 128; stride >= 1; stride >>= 1) {
    __syncthreads();
    if (tid < stride) {
      unsigned long long outk[16];
      int pa = 0, pb = 0;
#pragma unroll
      for (int k = 0; k < 16; k++) {
        unsigned long long va = sk[tid][pa], vb = sk[tid + stride][pb];
        if (va >= vb) { outk[k] = va; pa++; }
        else          { outk[k] = vb; pb++; }
      }
#pragma unroll
      for (int k = 0; k < 16; k++) sk[tid][k] = outk[k];
    }
  }
  __syncthreads();

  // exact f64 rescore of the 16 candidates (1 wave each, 4 rounds)
  const int lane = tid & 63, w = tid >> 6;
  for (int c = w; c < 16; c += 4) {
    int q = (int)(0xFFFFFFFFu - (unsigned)(sk[0][c] & 0xFFFFFFFFull));
    const float* sr = SUPn + (size_t)q * D;
    double dot = 0.0;
#pragma unroll
    for (int i = 0; i < 12; i++)
      dot += (double)sr[lane + 64 * i] * (double)tsrow[lane + 64 * i];
#pragma unroll
    for (int m = 32; m; m >>= 1) dot += __shfl_xor(dot, m);
    if (lane == 0) { sval[c] = dot; sidx[c] = q; }
  }
  __syncthreads();
  if (tid == 0) {
    for (int i = 1; i < 16; i++) {
      double v = sval[i]; int ix = sidx[i];
      int j = i - 1;
      while (j >= 0 && (sval[j] < v || (sval[j] == v && sidx[j] > ix))) {
        sval[j + 1] = sval[j]; sidx[j + 1] = sidx[j]; j--;
      }
      sval[j + 1] = v; sidx[j + 1] = ix;
    }
  }
  __syncthreads();

  // gather top-8 rows to output + positive mean + pos_sim
  float mean[3] = {0.f, 0.f, 0.f};
#pragma unroll
  for (int k = 0; k < 8; k++) {
    const float* sr = SUPn + (size_t)sidx[k] * D;
    float* orow = out + ((size_t)b * 8 + k) * D;
#pragma unroll
    for (int j = 0; j < 3; j++) {
      float x = sr[tid + 256 * j];
      orow[tid + 256 * j] = x;
      mean[j] += x;
    }
  }
#pragma unroll
  for (int j = 0; j < 3; j++) mean[j] *= 0.125f;
  double ss = 0.0;
#pragma unroll
  for (int j = 0; j < 3; j++) ss += (double)mean[j] * mean[j];
  ss = blk_sum(ss, red);
  double inv = 1.0 / fmax(sqrt(ss), 1e-12);
  double dot = 0.0;
#pragma unroll
  for (int j = 0; j < 3; j++)
    dot += (double)tsrow[tid + 256 * j] * ((double)mean[j] * inv);
  dot = blk_sum(dot, red);
  const double p = dot / (double)0.07f;

  // NNCL logsumexp over columns c = tid
  const float* tc = TSn + (size_t)tid * D;
  double dot2 = 0.0;
  for (int e = 0; e < D; e += 4) {
    float4 t4 = *(const float4*)(tc + e);
    dot2 += (double)tsrow[e] * t4.x + (double)tsrow[e + 1] * t4.y +
            (double)tsrow[e + 2] * t4.z + (double)tsrow[e + 3] * t4.w;
  }
  const bool diag = (tid == b);
  double logit = dot2 / (double)0.07f;
  double m = blk_max(diag ? -1e300 : logit, red);
  m = fmax(m, p);
  double term = diag ? 0.0 : exp(logit - m);
  double ssum = blk_sum(term, red);
  ssum += exp(p - m);
  if (tid == 0) row_loss[b] = (log(ssum) + m) - p;
}

// ---------------- K5: combine proto maxes -> partial loss sums --------------
__global__ __launch_bounds__(256) void reduce_proto(
    const float* __restrict__ maxpart, const float* __restrict__ wscale,
    double* __restrict__ accd, int V, int vstride) {
  __shared__ double red[4];
  const int v = blockIdx.x * 256 + threadIdx.x;
  double s = 0.0;
  if (v < V) {
    float mx = -1e30f;
#pragma unroll
    for (int g = 0; g < 16; g++)
      mx = fmaxf(mx, maxpart[(size_t)g * vstride + v]);
    s = 2.0 - 2.0 * (double)mx * (double)wscale[v];
  }
  s = blk_sum(s, red);
  if (threadIdx.x == 0) atomicAdd(accd, s);
}

// ---------------- K6: finalize scalars --------------------------------------
__global__ __launch_bounds__(256) void finalize(const double* __restrict__ accd,
                                                const double* __restrict__ row_loss,
                                                float* __restrict__ d_out, int out_size,
                                                int V, int B) {
  __shared__ double red[4];
  const int tid = threadIdx.x;
  double s2 = 0.0;
  for (int b = tid; b < B; b += 256) s2 += row_loss[b];
  s2 = blk_sum(s2, red);
  if (tid == 0) {
    d_out[out_size - 2] = (float)(accd[0] / ((double)V * (double)D));
    d_out[out_size - 1] = (float)(s2 / (double)B);
  }
}

// ---------------- host launcher ---------------------------------------------
extern "C" void kernel_launch(void* const* d_in, const int* in_sizes, int n_in,
                              void* d_out, int out_size, void* d_ws, size_t ws_size,
                              hipStream_t stream) {
  const float* TS  = (const float*)d_in[0];
  const float* W   = (const float*)d_in[1];
  const float* T   = (const float*)d_in[2];
  const float* SUP = (const float*)d_in[3];
  const int B = in_sizes[0] / D;   // 256
  const int V = in_sizes[1] / D;   // 50257
  const int U = in_sizes[2] / D;   // 1000
  const int Q = in_sizes[3] / D;   // 10000
  const int VPAD = (V + 255) & ~255; // 50432
  const int QPAD = (Q + 63) & ~63; // 10048
  const int NTB  = B / 16;         // 16
  const int nbT  = 1024 / 4;       // 256
  const int nbTS = B / 4;          // 64
  const int nbSUP = (Q + 3) / 4;   // 2500
  const int nbW  = VPAD / 64;      // 788 (wave = 16-row tile, 4 tiles/block)

  char* ws = (char*)d_ws;
  size_t off = 0;
  auto alloc = [&](size_t bytes) -> char* {
    char* p = ws + off;
    off = (off + bytes + 255) & ~(size_t)255;
    return p;
  };
  u64_t*  t8T    = (u64_t*) alloc((size_t)96 * 1024 * 8);       // 786 KB
  u64_t*  w8t    = (u64_t*) alloc((size_t)(VPAD / 16) * 1536 * 8); // 38.7 MB
  float*  wscale = (float*) alloc((size_t)VPAD * 4);
  float*  maxpart= (float*) alloc((size_t)16 * VPAD * 4);       // 3.2 MB
  float*  ts_n   = (float*) alloc((size_t)B * D * 4);
  bf16_t* ts_bf  = (bf16_t*)alloc((size_t)B * D * 2);
  float*  sup_n  = (float*) alloc((size_t)Q * D * 4);
  float*  simf   = (float*) alloc((size_t)B * QPAD * 4);
  double* rloss  = (double*)alloc((size_t)B * 8);
  double* accd   = (double*)alloc(8);
  (void)ws_size; (void)n_in;

  norm_all<<<nbT + nbTS + nbSUP + nbW, 256, 0, stream>>>(
      T, TS, SUP, W, t8T, w8t, wscale, ts_n, ts_bf, sup_n, accd,
      U, V, B, Q, nbT, nbTS, nbSUP);

  dim3 gms(16, VPAD / 256);  // x = proto-group, y = W-range (256 rows)
  maxsim_gemm<<<gms, 256, 0, stream>>>(w8t, t8T, maxpart, U, VPAD);

  simf_gemm<<<QPAD / 64, 256, 0, stream>>>(sup_n, ts_bf, simf, Q, QPAD, NTB);
  topk_nncl<<<B, 256, 0, stream>>>(simf, sup_n, ts_n, (float*)d_out, rloss, Q, QPAD);
  reduce_proto<<<VPAD / 256, 256, 0, stream>>>(maxpart, wscale, accd, V, VPAD);
  finalize<<<1, 256, 0, stream>>>(accd, rloss, (float*)d_out, out_size, V, B);
}